// Round 2
// baseline (550.440 us; speedup 1.0000x reference)
//
#include <hip/hip_runtime.h>

// TGNN encoder, fused single kernel: one block per batch row.
// B=1024, N=200, DN=DT=128, M=384.
// d_out layout: [ out (1024*128 f32) | attn_w (1024*200 f32) ]
//
// R2: (a) key loop chunked by 10 -> 30 global loads in flight/wave and 10
//     interleaved butterfly-reduce chains (was: 3 loads + 1 serialized chain
//     per key -> latency-bound, VALUBusy 12.7%, HBM 8.9%).
//     (b) FC/FC1/FC2 are per-thread-output GEMVs (no cross-lane shuffles);
//     activations read from LDS as wave-uniform broadcast, weight rows as
//     per-thread float4 streams (weights are L2-resident, 1.2 MB total).

constexpr int B_  = 1024;
constexpr int N_  = 200;
constexpr int DN_ = 128;
constexpr int M_  = 384;     // DN + DN + DT
constexpr int BDIM = 256;    // 4 waves
constexpr int NPW  = N_ / 4; // 50 keys per wave
constexpr int CH   = 10;     // keys per chunk

__device__ __forceinline__ float wave_sum(float v) {
#pragma unroll
    for (int off = 32; off > 0; off >>= 1)
        v += __shfl_xor(v, off, 64);
    return v;
}

__global__ __launch_bounds__(BDIM, 4) void tgnn_kernel(
    const float* __restrict__ src,      // (B, DN)
    const float* __restrict__ src_t,    // (B, 1, DT)
    const float* __restrict__ seq,      // (B, N, DN)
    const float* __restrict__ seq_t,    // (B, N, DT)
    const float* __restrict__ seq_e,    // (B, N, DN)
    const int*   __restrict__ mask,     // (B, N) int32 (bool)
    const float* __restrict__ shared_attn, // (2M,)
    const float* __restrict__ fc_w,     // (M, M)
    const float* __restrict__ ln_g,     // (M,)
    const float* __restrict__ ln_b,     // (M,)
    const float* __restrict__ w1,       // (2DN, M+DN) = (256, 512)
    const float* __restrict__ w2,       // (DN, 2DN)   = (128, 256)
    float* __restrict__ out,            // (B, DN)
    float* __restrict__ attn_out)       // (B, N)
{
    const int b    = blockIdx.x;
    const int tid  = threadIdx.x;
    const int wave = tid >> 6;
    const int lane = tid & 63;
    const int e0   = 2 * lane;      // this lane's element pair within a 128-slice

    __shared__ float s_p[N_];                     // unnormalized exp(score)
    __shared__ __align__(16) float s_q[M_];       // q = [src, 0, src_t]
    __shared__ float s_oa[4][M_];                 // per-wave attention accumulators
    __shared__ __align__(16) float s_outattn[M_]; // attn @ k
    __shared__ __align__(16) float s_y[M_ + DN_]; // LN output, then concat src -> x[512]
    __shared__ __align__(16) float s_h[2 * DN_];  // relu(x @ w1.T)
    __shared__ float s_red[8];

    // ---- stage q into LDS ----
    if (tid < 128) {
        s_q[tid]       = src[b * DN_ + tid];
        s_q[128 + tid] = 0.0f;
        s_q[256 + tid] = src_t[b * DN_ + tid];
    }

    // ---- per-lane wk fragment (elements e0,e0+1 of each 128-slice) ----
    const float* wq = shared_attn;        // [0, M)
    const float* wk = shared_attn + M_;   // [M, 2M)
    const float wk0 = wk[e0],       wk1 = wk[e0 + 1];
    const float wk2 = wk[128 + e0], wk3 = wk[128 + e0 + 1];
    const float wk4 = wk[256 + e0], wk5 = wk[256 + e0 + 1];

    // ---- q-side score (constant over n) ----
    float qpart = src[b * DN_ + e0]     * wq[e0]
                + src[b * DN_ + e0 + 1] * wq[e0 + 1]
                + src_t[b * DN_ + e0]     * wq[256 + e0]
                + src_t[b * DN_ + e0 + 1] * wq[256 + e0 + 1];
    const float qdot = wave_sum(qpart);

    // ---- fused score + weighted-sum pass, chunked by CH keys ----
    float o0 = 0.f, o1 = 0.f, o2 = 0.f, o3 = 0.f, o4 = 0.f, o5 = 0.f;
    float lsum = 0.f;
    const int n_base = wave * NPW;
    for (int c = 0; c < NPW / CH; ++c) {
        const int n0 = n_base + c * CH;
        float2 a[CH], e[CH], t[CH];
        int mk[CH];
#pragma unroll
        for (int j = 0; j < CH; ++j) {
            const long row = (long)(b * N_ + n0 + j);
            a[j] = *(const float2*)&seq  [row * DN_ + e0];
            e[j] = *(const float2*)&seq_e[row * DN_ + e0];
            t[j] = *(const float2*)&seq_t[row * DN_ + e0];
            mk[j] = mask[row];
        }
        float s[CH];
#pragma unroll
        for (int j = 0; j < CH; ++j)
            s[j] = a[j].x * wk0 + a[j].y * wk1
                 + e[j].x * wk2 + e[j].y * wk3
                 + t[j].x * wk4 + t[j].y * wk5;
        // 10 independent butterfly chains, interleaved (off outer, key inner)
#pragma unroll
        for (int off = 32; off > 0; off >>= 1) {
#pragma unroll
            for (int j = 0; j < CH; ++j)
                s[j] += __shfl_xor(s[j], off, 64);
        }
#pragma unroll
        for (int j = 0; j < CH; ++j) {
            const float p = mk[j] ? 0.0f : __expf(s[j] + qdot);
            if (lane == j) s_p[n0 + j] = p;   // p uniform across lanes
            lsum += p;
            o0 += p * a[j].x; o1 += p * a[j].y;
            o2 += p * e[j].x; o3 += p * e[j].y;
            o4 += p * t[j].x; o5 += p * t[j].y;
        }
    }

    // ---- combine 4 waves ----
    if (lane == 0) s_red[wave] = lsum;
    s_oa[wave][e0]           = o0; s_oa[wave][e0 + 1]       = o1;
    s_oa[wave][128 + e0]     = o2; s_oa[wave][128 + e0 + 1] = o3;
    s_oa[wave][256 + e0]     = o4; s_oa[wave][256 + e0 + 1] = o5;
    __syncthreads();

    const float Z    = s_red[0] + s_red[1] + s_red[2] + s_red[3];
    const float invZ = 1.0f / Z;

    for (int j = tid; j < M_; j += BDIM)
        s_outattn[j] = (s_oa[0][j] + s_oa[1][j] + s_oa[2][j] + s_oa[3][j]) * invZ;
    for (int n = tid; n < N_; n += BDIM)
        attn_out[b * N_ + n] = s_p[n] * invZ;
    __syncthreads();

    // ---- fc: s_y[i] = dot(s_outattn, fc_w[i,:]) + q[i], per-thread outputs ----
    const float4* xa = (const float4*)s_outattn;
    for (int i = tid; i < M_; i += BDIM) {
        const float4* row = (const float4*)&fc_w[i * M_];
        float acc = 0.f;
#pragma unroll
        for (int j = 0; j < M_ / 4; ++j) {
            const float4 w = row[j];
            const float4 x = xa[j];
            acc += w.x * x.x + w.y * x.y + w.z * x.z + w.w * x.w;
        }
        s_y[i] = acc + s_q[i];
    }
    __syncthreads();

    // ---- layer norm over M ----
    float ls = 0.f, lq = 0.f;
    for (int j = tid; j < M_; j += BDIM) {
        const float v = s_y[j];
        ls += v; lq += v * v;
    }
    ls = wave_sum(ls); lq = wave_sum(lq);
    if (lane == 0) { s_red[wave] = ls; s_red[4 + wave] = lq; }
    __syncthreads();
    const float mean = (s_red[0] + s_red[1] + s_red[2] + s_red[3]) * (1.0f / M_);
    const float msq  = (s_red[4] + s_red[5] + s_red[6] + s_red[7]) * (1.0f / M_);
    const float rstd = rsqrtf(msq - mean * mean + 1e-5f);
    for (int j = tid; j < M_; j += BDIM)
        s_y[j] = (s_y[j] - mean) * rstd * ln_g[j] + ln_b[j];
    if (tid < 128)
        s_y[M_ + tid] = s_q[tid];               // concat src
    __syncthreads();

    // ---- agg fc1: s_h[i] = relu(dot(s_y[512], w1[i,:])), one output/thread ----
    {
        const float4* xb = (const float4*)s_y;
        const float4* row = (const float4*)&w1[tid * (M_ + DN_)];
        float acc = 0.f;
#pragma unroll
        for (int j = 0; j < (M_ + DN_) / 4; ++j) {
            const float4 w = row[j];
            const float4 x = xb[j];
            acc += w.x * x.x + w.y * x.y + w.z * x.z + w.w * x.w;
        }
        s_h[tid] = fmaxf(acc, 0.0f);
    }
    __syncthreads();

    // ---- agg fc2: out[i] = dot(s_h[256], w2[i,:]), threads 0..127 ----
    if (tid < DN_) {
        const float4* xc = (const float4*)s_h;
        const float4* row = (const float4*)&w2[tid * (2 * DN_)];
        float acc = 0.f;
#pragma unroll
        for (int j = 0; j < (2 * DN_) / 4; ++j) {
            const float4 w = row[j];
            const float4 x = xc[j];
            acc += w.x * x.x + w.y * x.y + w.z * x.z + w.w * x.w;
        }
        out[b * DN_ + tid] = acc;
    }
}

extern "C" void kernel_launch(void* const* d_in, const int* in_sizes, int n_in,
                              void* d_out, int out_size, void* d_ws, size_t ws_size,
                              hipStream_t stream) {
    const float* src         = (const float*)d_in[0];
    const float* src_t       = (const float*)d_in[1];
    const float* seq         = (const float*)d_in[2];
    const float* seq_t       = (const float*)d_in[3];
    const float* seq_e       = (const float*)d_in[4];
    const int*   mask        = (const int*)  d_in[5];
    const float* shared_attn = (const float*)d_in[6];
    const float* fc_w        = (const float*)d_in[7];
    const float* ln_g        = (const float*)d_in[8];
    const float* ln_b        = (const float*)d_in[9];
    const float* w1          = (const float*)d_in[10];
    const float* w2          = (const float*)d_in[11];

    float* outp     = (float*)d_out;             // (B, DN)
    float* attn_out = (float*)d_out + B_ * DN_;  // (B, N)

    tgnn_kernel<<<B_, BDIM, 0, stream>>>(src, src_t, seq, seq_t, seq_e, mask,
                                         shared_attn, fc_w, ln_g, ln_b, w1, w2,
                                         outp, attn_out);
}

// Round 3
// 480.584 us; speedup vs baseline: 1.1454x; 1.1454x over previous
//
#include <hip/hip_runtime.h>

// TGNN encoder, fused single kernel: one block per batch row.
// B=1024, N=200, DN=DT=128, M=384.
// d_out layout: [ out (1024*128 f32) | attn_w (1024*200 f32) ]
//
// R3: R2's launch_bounds(256,4) clamped VGPR to 64 and spilled the CH=10
//     chunk arrays to scratch (WRITE_SIZE 1.3->228 MB!). Fix: no occupancy
//     clamp (grid only supplies 4 blocks/CU anyway), and fold the mask into
//     the pre-reduce partial (pen/64 summed over 64 lanes == -1e10 exactly)
//     so the mk[] array dies at load. Keep: CH=10 loads-in-flight, 10
//     interleaved butterfly chains, per-thread-output FC GEMVs.

constexpr int B_  = 1024;
constexpr int N_  = 200;
constexpr int DN_ = 128;
constexpr int M_  = 384;     // DN + DN + DT
constexpr int BDIM = 256;    // 4 waves
constexpr int NPW  = N_ / 4; // 50 keys per wave
constexpr int CH   = 10;     // keys per chunk

__device__ __forceinline__ float wave_sum(float v) {
#pragma unroll
    for (int off = 32; off > 0; off >>= 1)
        v += __shfl_xor(v, off, 64);
    return v;
}

__global__ __launch_bounds__(BDIM) void tgnn_kernel(
    const float* __restrict__ src,      // (B, DN)
    const float* __restrict__ src_t,    // (B, 1, DT)
    const float* __restrict__ seq,      // (B, N, DN)
    const float* __restrict__ seq_t,    // (B, N, DT)
    const float* __restrict__ seq_e,    // (B, N, DN)
    const int*   __restrict__ mask,     // (B, N) int32 (bool)
    const float* __restrict__ shared_attn, // (2M,)
    const float* __restrict__ fc_w,     // (M, M)
    const float* __restrict__ ln_g,     // (M,)
    const float* __restrict__ ln_b,     // (M,)
    const float* __restrict__ w1,       // (2DN, M+DN) = (256, 512)
    const float* __restrict__ w2,       // (DN, 2DN)   = (128, 256)
    float* __restrict__ out,            // (B, DN)
    float* __restrict__ attn_out)       // (B, N)
{
    const int b    = blockIdx.x;
    const int tid  = threadIdx.x;
    const int wave = tid >> 6;
    const int lane = tid & 63;
    const int e0   = 2 * lane;      // this lane's element pair within a 128-slice

    __shared__ float s_p[N_];                     // unnormalized exp(score)
    __shared__ __align__(16) float s_q[M_];       // q = [src, 0, src_t]
    __shared__ float s_oa[4][M_];                 // per-wave attention accumulators
    __shared__ __align__(16) float s_outattn[M_]; // attn @ k
    __shared__ __align__(16) float s_y[M_ + DN_]; // LN output, then concat src -> x[512]
    __shared__ __align__(16) float s_h[2 * DN_];  // relu(x @ w1.T)
    __shared__ float s_red[8];

    // ---- stage q into LDS ----
    if (tid < 128) {
        s_q[tid]       = src[b * DN_ + tid];
        s_q[128 + tid] = 0.0f;
        s_q[256 + tid] = src_t[b * DN_ + tid];
    }

    // ---- per-lane wk fragment (elements e0,e0+1 of each 128-slice) ----
    const float* wq = shared_attn;        // [0, M)
    const float* wk = shared_attn + M_;   // [M, 2M)
    const float wk0 = wk[e0],       wk1 = wk[e0 + 1];
    const float wk2 = wk[128 + e0], wk3 = wk[128 + e0 + 1];
    const float wk4 = wk[256 + e0], wk5 = wk[256 + e0 + 1];

    // ---- q-side score (constant over n) ----
    float qpart = src[b * DN_ + e0]     * wq[e0]
                + src[b * DN_ + e0 + 1] * wq[e0 + 1]
                + src_t[b * DN_ + e0]     * wq[256 + e0]
                + src_t[b * DN_ + e0 + 1] * wq[256 + e0 + 1];
    const float qdot = wave_sum(qpart);

    // ---- fused score + weighted-sum pass, chunked by CH keys ----
    float o0 = 0.f, o1 = 0.f, o2 = 0.f, o3 = 0.f, o4 = 0.f, o5 = 0.f;
    float lsum = 0.f;
    const int n_base = wave * NPW;
    for (int c = 0; c < NPW / CH; ++c) {
        const int n0 = n_base + c * CH;
        float2 a[CH], e[CH], t[CH];
        float s[CH];
#pragma unroll
        for (int j = 0; j < CH; ++j) {
            const long row = (long)(b * N_ + n0 + j);
            a[j] = *(const float2*)&seq  [row * DN_ + e0];
            e[j] = *(const float2*)&seq_e[row * DN_ + e0];
            t[j] = *(const float2*)&seq_t[row * DN_ + e0];
            // masked key: every lane adds -1e10/64 -> summed score -1e10 -> exp==0
            s[j] = mask[row] ? -156250000.0f : 0.0f;
        }
#pragma unroll
        for (int j = 0; j < CH; ++j)
            s[j] += a[j].x * wk0 + a[j].y * wk1
                  + e[j].x * wk2 + e[j].y * wk3
                  + t[j].x * wk4 + t[j].y * wk5;
        // CH independent butterfly chains, interleaved (off outer, key inner)
#pragma unroll
        for (int off = 32; off > 0; off >>= 1) {
#pragma unroll
            for (int j = 0; j < CH; ++j)
                s[j] += __shfl_xor(s[j], off, 64);
        }
#pragma unroll
        for (int j = 0; j < CH; ++j) {
            const float p = __expf(s[j] + qdot);
            if (lane == j) s_p[n0 + j] = p;   // p uniform across lanes
            lsum += p;
            o0 += p * a[j].x; o1 += p * a[j].y;
            o2 += p * e[j].x; o3 += p * e[j].y;
            o4 += p * t[j].x; o5 += p * t[j].y;
        }
    }

    // ---- combine 4 waves ----
    if (lane == 0) s_red[wave] = lsum;
    s_oa[wave][e0]           = o0; s_oa[wave][e0 + 1]       = o1;
    s_oa[wave][128 + e0]     = o2; s_oa[wave][128 + e0 + 1] = o3;
    s_oa[wave][256 + e0]     = o4; s_oa[wave][256 + e0 + 1] = o5;
    __syncthreads();

    const float Z    = s_red[0] + s_red[1] + s_red[2] + s_red[3];
    const float invZ = 1.0f / Z;

    for (int j = tid; j < M_; j += BDIM)
        s_outattn[j] = (s_oa[0][j] + s_oa[1][j] + s_oa[2][j] + s_oa[3][j]) * invZ;
    for (int n = tid; n < N_; n += BDIM)
        attn_out[b * N_ + n] = s_p[n] * invZ;
    __syncthreads();

    // ---- fc: s_y[i] = dot(s_outattn, fc_w[i,:]) + q[i], per-thread outputs ----
    const float4* xa = (const float4*)s_outattn;
    for (int i = tid; i < M_; i += BDIM) {
        const float4* row = (const float4*)&fc_w[i * M_];
        float acc = 0.f;
#pragma unroll
        for (int j = 0; j < M_ / 4; ++j) {
            const float4 w = row[j];
            const float4 x = xa[j];
            acc += w.x * x.x + w.y * x.y + w.z * x.z + w.w * x.w;
        }
        s_y[i] = acc + s_q[i];
    }
    __syncthreads();

    // ---- layer norm over M ----
    float ls = 0.f, lq = 0.f;
    for (int j = tid; j < M_; j += BDIM) {
        const float v = s_y[j];
        ls += v; lq += v * v;
    }
    ls = wave_sum(ls); lq = wave_sum(lq);
    if (lane == 0) { s_red[wave] = ls; s_red[4 + wave] = lq; }
    __syncthreads();
    const float mean = (s_red[0] + s_red[1] + s_red[2] + s_red[3]) * (1.0f / M_);
    const float msq  = (s_red[4] + s_red[5] + s_red[6] + s_red[7]) * (1.0f / M_);
    const float rstd = rsqrtf(msq - mean * mean + 1e-5f);
    for (int j = tid; j < M_; j += BDIM)
        s_y[j] = (s_y[j] - mean) * rstd * ln_g[j] + ln_b[j];
    if (tid < 128)
        s_y[M_ + tid] = s_q[tid];               // concat src
    __syncthreads();

    // ---- agg fc1: s_h[i] = relu(dot(s_y[512], w1[i,:])), one output/thread ----
    {
        const float4* xb = (const float4*)s_y;
        const float4* row = (const float4*)&w1[tid * (M_ + DN_)];
        float acc = 0.f;
#pragma unroll
        for (int j = 0; j < (M_ + DN_) / 4; ++j) {
            const float4 w = row[j];
            const float4 x = xb[j];
            acc += w.x * x.x + w.y * x.y + w.z * x.z + w.w * x.w;
        }
        s_h[tid] = fmaxf(acc, 0.0f);
    }
    __syncthreads();

    // ---- agg fc2: out[i] = dot(s_h[256], w2[i,:]), threads 0..127 ----
    if (tid < DN_) {
        const float4* xc = (const float4*)s_h;
        const float4* row = (const float4*)&w2[tid * (2 * DN_)];
        float acc = 0.f;
#pragma unroll
        for (int j = 0; j < (2 * DN_) / 4; ++j) {
            const float4 w = row[j];
            const float4 x = xc[j];
            acc += w.x * x.x + w.y * x.y + w.z * x.z + w.w * x.w;
        }
        out[b * DN_ + tid] = acc;
    }
}

extern "C" void kernel_launch(void* const* d_in, const int* in_sizes, int n_in,
                              void* d_out, int out_size, void* d_ws, size_t ws_size,
                              hipStream_t stream) {
    const float* src         = (const float*)d_in[0];
    const float* src_t       = (const float*)d_in[1];
    const float* seq         = (const float*)d_in[2];
    const float* seq_t       = (const float*)d_in[3];
    const float* seq_e       = (const float*)d_in[4];
    const int*   mask        = (const int*)  d_in[5];
    const float* shared_attn = (const float*)d_in[6];
    const float* fc_w        = (const float*)d_in[7];
    const float* ln_g        = (const float*)d_in[8];
    const float* ln_b        = (const float*)d_in[9];
    const float* w1          = (const float*)d_in[10];
    const float* w2          = (const float*)d_in[11];

    float* outp     = (float*)d_out;             // (B, DN)
    float* attn_out = (float*)d_out + B_ * DN_;  // (B, N)

    tgnn_kernel<<<B_, BDIM, 0, stream>>>(src, src_t, seq, seq_t, seq_e, mask,
                                         shared_attn, fc_w, ln_g, ln_b, w1, w2,
                                         outp, attn_out);
}